// Round 1
// baseline (724.064 us; speedup 1.0000x reference)
//
#include <hip/hip_runtime.h>
#include <cstdint>
#include <cstddef>

// Problem constants
#define T_TOK 8192    // B*S tokens
#define DM    2048    // d_model
#define DI    4096    // d_inner
#define TWO_DI 8192

typedef __attribute__((ext_vector_type(8))) short bf16x8;
typedef __attribute__((ext_vector_type(4))) float f32x4;

__device__ __forceinline__ unsigned short f2bf(float f) {
  union { float f; unsigned u; } c; c.f = f;
  unsigned u = c.u;
  unsigned r = (u + 0x7fffu + ((u >> 16) & 1u)) >> 16;  // RNE
  return (unsigned short)r;
}
__device__ __forceinline__ float bf2f(unsigned short b) {
  union { unsigned u; float f; } c; c.u = ((unsigned)b) << 16;
  return c.f;
}

// ---------------------------------------------------------------------------
// LayerNorm over last dim (2048) + cast to bf16. One block per token.
// ---------------------------------------------------------------------------
__global__ __launch_bounds__(256) void ln_kernel(
    const float* __restrict__ x, const float* __restrict__ gamma,
    const float* __restrict__ beta, unsigned short* __restrict__ xn) {
  const int t = blockIdx.x;
  const int tid = threadIdx.x;
  const float* row = x + (size_t)t * DM;
  float4 v0 = reinterpret_cast<const float4*>(row)[tid];
  float4 v1 = reinterpret_cast<const float4*>(row)[tid + 256];
  float s  = v0.x + v0.y + v0.z + v0.w + v1.x + v1.y + v1.z + v1.w;
  float ss = v0.x*v0.x + v0.y*v0.y + v0.z*v0.z + v0.w*v0.w
           + v1.x*v1.x + v1.y*v1.y + v1.z*v1.z + v1.w*v1.w;
  #pragma unroll
  for (int off = 32; off > 0; off >>= 1) {
    s  += __shfl_down(s, off);
    ss += __shfl_down(ss, off);
  }
  __shared__ float red[8];
  __shared__ float mu_s, inv_s;
  if ((tid & 63) == 0) { red[tid >> 6] = s; red[4 + (tid >> 6)] = ss; }
  __syncthreads();
  if (tid == 0) {
    float S  = red[0] + red[1] + red[2] + red[3];
    float SS = red[4] + red[5] + red[6] + red[7];
    float mu  = S * (1.0f / DM);
    float var = SS * (1.0f / DM) - mu * mu;
    mu_s = mu;
    inv_s = rsqrtf(var + 1e-5f);
  }
  __syncthreads();
  const float mu = mu_s, inv = inv_s;
  float4 g0 = reinterpret_cast<const float4*>(gamma)[tid];
  float4 b0 = reinterpret_cast<const float4*>(beta)[tid];
  float4 g1 = reinterpret_cast<const float4*>(gamma)[tid + 256];
  float4 b1 = reinterpret_cast<const float4*>(beta)[tid + 256];
  ushort4 o0, o1;
  o0.x = f2bf((v0.x - mu) * inv * g0.x + b0.x);
  o0.y = f2bf((v0.y - mu) * inv * g0.y + b0.y);
  o0.z = f2bf((v0.z - mu) * inv * g0.z + b0.z);
  o0.w = f2bf((v0.w - mu) * inv * g0.w + b0.w);
  o1.x = f2bf((v1.x - mu) * inv * g1.x + b1.x);
  o1.y = f2bf((v1.y - mu) * inv * g1.y + b1.y);
  o1.z = f2bf((v1.z - mu) * inv * g1.z + b1.z);
  o1.w = f2bf((v1.w - mu) * inv * g1.w + b1.w);
  reinterpret_cast<ushort4*>(xn + (size_t)t * DM)[tid]       = o0;
  reinterpret_cast<ushort4*>(xn + (size_t)t * DM)[tid + 256] = o1;
}

// ---------------------------------------------------------------------------
// fp32 -> bf16 conversion (vectorized x4)
// ---------------------------------------------------------------------------
__global__ __launch_bounds__(256) void cvt_bf16(
    const float* __restrict__ in, unsigned short* __restrict__ out, int n4) {
  int i = blockIdx.x * 256 + threadIdx.x;
  if (i >= n4) return;
  float4 v = reinterpret_cast<const float4*>(in)[i];
  ushort4 o;
  o.x = f2bf(v.x); o.y = f2bf(v.y); o.z = f2bf(v.z); o.w = f2bf(v.w);
  reinterpret_cast<ushort4*>(out)[i] = o;
}

// ---------------------------------------------------------------------------
// softmax(-dt) over 4096 elems. Single block.
// ---------------------------------------------------------------------------
__global__ __launch_bounds__(256) void dt_softmax(
    const float* __restrict__ dt, float* __restrict__ w) {
  const int tid = threadIdx.x;
  float e[16];
  float local = 0.f;
  #pragma unroll
  for (int i = 0; i < 16; ++i) {
    float v = __expf(-dt[i * 256 + tid]);
    e[i] = v;
    local += v;
  }
  #pragma unroll
  for (int off = 32; off > 0; off >>= 1) local += __shfl_down(local, off);
  __shared__ float red[4];
  __shared__ float tot;
  if ((tid & 63) == 0) red[tid >> 6] = local;
  __syncthreads();
  if (tid == 0) tot = red[0] + red[1] + red[2] + red[3];
  __syncthreads();
  const float inv = 1.f / tot;
  #pragma unroll
  for (int i = 0; i < 16; ++i) w[i * 256 + tid] = e[i] * inv;
}

// ---------------------------------------------------------------------------
// Gated activation: out[t,e] = z*sigmoid(clip(z)) * dtw[e] * clip(g)*sigmoid(clip(g))
// z = proj[t,e], g = proj[t,e+DI]. Writes bf16 act[t,e].
// ---------------------------------------------------------------------------
__device__ __forceinline__ float actf(float z, float g, float w) {
  float zc = fminf(fmaxf(z, -15.f), 15.f);
  float sz = 1.f / (1.f + __expf(-zc));
  float gc = fminf(fmaxf(g, -15.f), 15.f);
  float sg = 1.f / (1.f + __expf(-gc));
  return z * sz * w * gc * sg;
}

__global__ __launch_bounds__(256) void act_kernel(
    const unsigned short* __restrict__ proj, const float* __restrict__ dtw,
    unsigned short* __restrict__ act) {
  const long i = (long)blockIdx.x * 256 + threadIdx.x;  // one thread = 4 elems
  const int  e4 = (int)(i & 1023);                      // DI/4 = 1024
  const long t  = i >> 10;
  const ushort4 z4 = *reinterpret_cast<const ushort4*>(proj + (t << 13) + (e4 << 2));
  const ushort4 g4 = *reinterpret_cast<const ushort4*>(proj + (t << 13) + DI + (e4 << 2));
  const float4  w4 = reinterpret_cast<const float4*>(dtw)[e4];
  ushort4 o;
  o.x = f2bf(actf(bf2f(z4.x), bf2f(g4.x), w4.x));
  o.y = f2bf(actf(bf2f(z4.y), bf2f(g4.y), w4.y));
  o.z = f2bf(actf(bf2f(z4.z), bf2f(g4.z), w4.z));
  o.w = f2bf(actf(bf2f(z4.w), bf2f(g4.w), w4.w));
  reinterpret_cast<ushort4*>(act)[i] = o;
}

// ---------------------------------------------------------------------------
// NT bf16 GEMM (m97 recipe): C[m,n] = sum_k A[m,k] * B[n,k]
// 128x128 tile, BK=64, 256 threads = 4 waves in 2x2, each wave 64x64 via
// 4x4 of 16x16x32 MFMA. global_load_lds width=16 staging (unpadded LDS).
// EPI=0: store bf16 C.  EPI=1: C += identity (fp32), store fp32.
// ---------------------------------------------------------------------------
#define BM 128
#define BN 128
#define BK 64

template <int EPI>
__global__ __launch_bounds__(256, 2) void gemm_nt(
    const unsigned short* __restrict__ A, const unsigned short* __restrict__ Bm,
    unsigned short* __restrict__ Cbf, float* __restrict__ Cf,
    const float* __restrict__ ident, int M, int N, int K) {
  __shared__ unsigned short lA[BM * BK];
  __shared__ unsigned short lB[BN * BK];
  const int tid  = threadIdx.x;
  const int lane = tid & 63;
  const int wave = tid >> 6;
  const int wm = (wave >> 1) << 6;  // wave row offset in tile
  const int wn = (wave & 1) << 6;   // wave col offset in tile
  const int tM = blockIdx.y * BM;
  const int tN = blockIdx.x * BN;

  f32x4 acc[4][4];
  #pragma unroll
  for (int i = 0; i < 4; ++i)
    #pragma unroll
    for (int j = 0; j < 4; ++j) acc[i][j] = f32x4{0.f, 0.f, 0.f, 0.f};

  const unsigned short* Ab = A + (size_t)tM * K;
  const unsigned short* Bb = Bm + (size_t)tN * K;

  for (int k0 = 0; k0 < K; k0 += BK) {
    // Stage A and B tiles (128x64 bf16 = 16 KB each): 4 x 16B per thread each.
    // LDS dest address = wave-uniform base + lane*16 (required by HW).
    #pragma unroll
    for (int i = 0; i < 4; ++i) {
      const int t8  = i * 256 + tid;
      const int row = t8 >> 3;           // 8 chunks of 16B per 64-elem row
      const int col = (t8 & 7) << 3;
      __builtin_amdgcn_global_load_lds(
          (const __attribute__((address_space(1))) void*)(Ab + (size_t)row * K + k0 + col),
          (__attribute__((address_space(3))) void*)(&lA[t8 << 3]), 16, 0, 0);
      __builtin_amdgcn_global_load_lds(
          (const __attribute__((address_space(1))) void*)(Bb + (size_t)row * K + k0 + col),
          (__attribute__((address_space(3))) void*)(&lB[t8 << 3]), 16, 0, 0);
    }
    __syncthreads();

    #pragma unroll
    for (int kk = 0; kk < BK; kk += 32) {
      const int r0 = lane & 15;
      const int ko = kk + ((lane >> 4) << 3);
      bf16x8 af[4], bfr[4];
      #pragma unroll
      for (int i = 0; i < 4; ++i)
        af[i] = *reinterpret_cast<const bf16x8*>(&lA[(wm + i * 16 + r0) * BK + ko]);
      #pragma unroll
      for (int j = 0; j < 4; ++j)
        bfr[j] = *reinterpret_cast<const bf16x8*>(&lB[(wn + j * 16 + r0) * BK + ko]);
      #pragma unroll
      for (int i = 0; i < 4; ++i)
        #pragma unroll
        for (int j = 0; j < 4; ++j)
          acc[i][j] = __builtin_amdgcn_mfma_f32_16x16x32_bf16(af[i], bfr[j], acc[i][j], 0, 0, 0);
    }
    __syncthreads();
  }

  // Epilogue. C/D layout: col = lane&15, row = (lane>>4)*4 + reg.
  const int cn = tN + wn + (lane & 15);
  const int rm = tM + wm + ((lane >> 4) << 2);
  #pragma unroll
  for (int i = 0; i < 4; ++i) {
    #pragma unroll
    for (int r = 0; r < 4; ++r) {
      const size_t rowoff = (size_t)(rm + i * 16 + r) * N;
      #pragma unroll
      for (int j = 0; j < 4; ++j) {
        const size_t idx = rowoff + cn + j * 16;
        const float v = acc[i][j][r];
        if (EPI == 0) {
          Cbf[idx] = f2bf(v);
        } else {
          Cf[idx] = v + ident[idx];
        }
      }
    }
  }
}

// ---------------------------------------------------------------------------
// Launch. Workspace layout (needs ~210 MB):
//   [0, 32MB)    xn bf16 [8192][2048]      (overlaid by act after GEMM1)
//   [32, 64MB)   W_in bf16 [8192][2048]    (overlaid by act after GEMM1)
//   [64, 80MB)   W_out bf16 [2048][4096]
//   [80MB, +16K) dt_weights fp32 [4096]
//   [81MB, +128MB) projected bf16 [8192][8192]
//   act bf16 [8192][4096] = 64MB overlays [0, 64MB)
// ---------------------------------------------------------------------------
extern "C" void kernel_launch(void* const* d_in, const int* in_sizes, int n_in,
                              void* d_out, int out_size, void* d_ws, size_t ws_size,
                              hipStream_t stream) {
  const float* x     = (const float*)d_in[0];
  const float* gamma = (const float*)d_in[1];
  const float* beta  = (const float*)d_in[2];
  const float* W_in  = (const float*)d_in[3];
  const float* W_out = (const float*)d_in[4];
  const float* dt    = (const float*)d_in[5];
  float* out = (float*)d_out;

  char* ws = (char*)d_ws;
  unsigned short* xn     = (unsigned short*)(ws);
  unsigned short* win_b  = (unsigned short*)(ws + ((size_t)32 << 20));
  unsigned short* wout_b = (unsigned short*)(ws + ((size_t)64 << 20));
  float*          dtw    = (float*)(ws + ((size_t)80 << 20));
  unsigned short* proj   = (unsigned short*)(ws + ((size_t)81 << 20));
  unsigned short* act    = (unsigned short*)(ws);  // overlays xn+W_in after GEMM1

  ln_kernel<<<T_TOK, 256, 0, stream>>>(x, gamma, beta, xn);
  cvt_bf16<<<(TWO_DI * DM / 4 + 255) / 256, 256, 0, stream>>>(W_in, win_b, TWO_DI * DM / 4);
  cvt_bf16<<<(DM * DI / 4 + 255) / 256, 256, 0, stream>>>(W_out, wout_b, DM * DI / 4);
  dt_softmax<<<1, 256, 0, stream>>>(dt, dtw);

  // GEMM1: proj[t,e] = sum_d xn[t,d] * W_in[e,d]   (M=8192, N=8192, K=2048)
  gemm_nt<0><<<dim3(TWO_DI / BN, T_TOK / BM), 256, 0, stream>>>(
      xn, win_b, proj, nullptr, nullptr, T_TOK, TWO_DI, DM);

  // Activation: act[t,e] = f(z, gate) * dtw[e]
  act_kernel<<<T_TOK * DI / 4 / 256, 256, 0, stream>>>(proj, dtw, act);

  // GEMM2: out[t,d] = sum_e act[t,e] * W_out[d,e] + x[t,d]  (M=8192, N=2048, K=4096)
  gemm_nt<1><<<dim3(DM / BN, T_TOK / BM), 256, 0, stream>>>(
      act, wout_b, nullptr, out, x, T_TOK, DM, DI);
}

// Round 2
// 604.506 us; speedup vs baseline: 1.1978x; 1.1978x over previous
//
#include <hip/hip_runtime.h>
#include <cstdint>
#include <cstddef>

// Problem constants
#define T_TOK 8192    // B*S tokens
#define DM    2048    // d_model
#define DI    4096    // d_inner
#define TWO_DI 8192

typedef __attribute__((ext_vector_type(8))) short bf16x8;
typedef __attribute__((ext_vector_type(4))) float f32x4;

__device__ __forceinline__ unsigned short f2bf(float f) {
  union { float f; unsigned u; } c; c.f = f;
  unsigned u = c.u;
  unsigned r = (u + 0x7fffu + ((u >> 16) & 1u)) >> 16;  // RNE
  return (unsigned short)r;
}
__device__ __forceinline__ float bf2f(unsigned short b) {
  union { unsigned u; float f; } c; c.u = ((unsigned)b) << 16;
  return c.f;
}

// ---------------------------------------------------------------------------
// LayerNorm over last dim (2048) + cast to bf16. One block per token.
// ---------------------------------------------------------------------------
__global__ __launch_bounds__(256) void ln_kernel(
    const float* __restrict__ x, const float* __restrict__ gamma,
    const float* __restrict__ beta, unsigned short* __restrict__ xn) {
  const int t = blockIdx.x;
  const int tid = threadIdx.x;
  const float* row = x + (size_t)t * DM;
  float4 v0 = reinterpret_cast<const float4*>(row)[tid];
  float4 v1 = reinterpret_cast<const float4*>(row)[tid + 256];
  float s  = v0.x + v0.y + v0.z + v0.w + v1.x + v1.y + v1.z + v1.w;
  float ss = v0.x*v0.x + v0.y*v0.y + v0.z*v0.z + v0.w*v0.w
           + v1.x*v1.x + v1.y*v1.y + v1.z*v1.z + v1.w*v1.w;
  #pragma unroll
  for (int off = 32; off > 0; off >>= 1) {
    s  += __shfl_down(s, off);
    ss += __shfl_down(ss, off);
  }
  __shared__ float red[8];
  __shared__ float mu_s, inv_s;
  if ((tid & 63) == 0) { red[tid >> 6] = s; red[4 + (tid >> 6)] = ss; }
  __syncthreads();
  if (tid == 0) {
    float S  = red[0] + red[1] + red[2] + red[3];
    float SS = red[4] + red[5] + red[6] + red[7];
    float mu  = S * (1.0f / DM);
    float var = SS * (1.0f / DM) - mu * mu;
    mu_s = mu;
    inv_s = rsqrtf(var + 1e-5f);
  }
  __syncthreads();
  const float mu = mu_s, inv = inv_s;
  float4 g0 = reinterpret_cast<const float4*>(gamma)[tid];
  float4 b0 = reinterpret_cast<const float4*>(beta)[tid];
  float4 g1 = reinterpret_cast<const float4*>(gamma)[tid + 256];
  float4 b1 = reinterpret_cast<const float4*>(beta)[tid + 256];
  ushort4 o0, o1;
  o0.x = f2bf((v0.x - mu) * inv * g0.x + b0.x);
  o0.y = f2bf((v0.y - mu) * inv * g0.y + b0.y);
  o0.z = f2bf((v0.z - mu) * inv * g0.z + b0.z);
  o0.w = f2bf((v0.w - mu) * inv * g0.w + b0.w);
  o1.x = f2bf((v1.x - mu) * inv * g1.x + b1.x);
  o1.y = f2bf((v1.y - mu) * inv * g1.y + b1.y);
  o1.z = f2bf((v1.z - mu) * inv * g1.z + b1.z);
  o1.w = f2bf((v1.w - mu) * inv * g1.w + b1.w);
  reinterpret_cast<ushort4*>(xn + (size_t)t * DM)[tid]       = o0;
  reinterpret_cast<ushort4*>(xn + (size_t)t * DM)[tid + 256] = o1;
}

// ---------------------------------------------------------------------------
// fp32 -> bf16 conversion (vectorized x4)
// ---------------------------------------------------------------------------
__global__ __launch_bounds__(256) void cvt_bf16(
    const float* __restrict__ in, unsigned short* __restrict__ out, int n4) {
  int i = blockIdx.x * 256 + threadIdx.x;
  if (i >= n4) return;
  float4 v = reinterpret_cast<const float4*>(in)[i];
  ushort4 o;
  o.x = f2bf(v.x); o.y = f2bf(v.y); o.z = f2bf(v.z); o.w = f2bf(v.w);
  reinterpret_cast<ushort4*>(out)[i] = o;
}

// ---------------------------------------------------------------------------
// softmax(-dt) over 4096 elems. Single block.
// ---------------------------------------------------------------------------
__global__ __launch_bounds__(256) void dt_softmax(
    const float* __restrict__ dt, float* __restrict__ w) {
  const int tid = threadIdx.x;
  float e[16];
  float local = 0.f;
  #pragma unroll
  for (int i = 0; i < 16; ++i) {
    float v = __expf(-dt[i * 256 + tid]);
    e[i] = v;
    local += v;
  }
  #pragma unroll
  for (int off = 32; off > 0; off >>= 1) local += __shfl_down(local, off);
  __shared__ float red[4];
  __shared__ float tot;
  if ((tid & 63) == 0) red[tid >> 6] = local;
  __syncthreads();
  if (tid == 0) tot = red[0] + red[1] + red[2] + red[3];
  __syncthreads();
  const float inv = 1.f / tot;
  #pragma unroll
  for (int i = 0; i < 16; ++i) w[i * 256 + tid] = e[i] * inv;
}

// ---------------------------------------------------------------------------
// Gated activation: out[t,e] = z*sigmoid(clip(z)) * dtw[e] * clip(g)*sigmoid(clip(g))
// ---------------------------------------------------------------------------
__device__ __forceinline__ float actf(float z, float g, float w) {
  float zc = fminf(fmaxf(z, -15.f), 15.f);
  float sz = 1.f / (1.f + __expf(-zc));
  float gc = fminf(fmaxf(g, -15.f), 15.f);
  float sg = 1.f / (1.f + __expf(-gc));
  return z * sz * w * gc * sg;
}

__global__ __launch_bounds__(256) void act_kernel(
    const unsigned short* __restrict__ proj, const float* __restrict__ dtw,
    unsigned short* __restrict__ act) {
  const long i = (long)blockIdx.x * 256 + threadIdx.x;  // one thread = 4 elems
  const int  e4 = (int)(i & 1023);                      // DI/4 = 1024
  const long t  = i >> 10;
  const ushort4 z4 = *reinterpret_cast<const ushort4*>(proj + (t << 13) + (e4 << 2));
  const ushort4 g4 = *reinterpret_cast<const ushort4*>(proj + (t << 13) + DI + (e4 << 2));
  const float4  w4 = reinterpret_cast<const float4*>(dtw)[e4];
  ushort4 o;
  o.x = f2bf(actf(bf2f(z4.x), bf2f(g4.x), w4.x));
  o.y = f2bf(actf(bf2f(z4.y), bf2f(g4.y), w4.y));
  o.z = f2bf(actf(bf2f(z4.z), bf2f(g4.z), w4.z));
  o.w = f2bf(actf(bf2f(z4.w), bf2f(g4.w), w4.w));
  reinterpret_cast<ushort4*>(act)[i] = o;
}

// ---------------------------------------------------------------------------
// NT bf16 GEMM (m97 recipe + XOR-swizzled LDS):
// C[m,n] = sum_k A[m,k] * B[n,k]
// 128x128 tile, BK=64, 256 threads = 4 waves in 2x2, each wave 64x64 via
// 4x4 of 16x16x32 MFMA.
//
// LDS swizzle: slot (row, s8) holds global chunk c8 = s8 ^ (row & 7).
// global_load_lds requires dest = wave-base + lane*16 (fixed), so we permute
// the *global source* per lane instead. Fragment reads then hit all 8
// four-bank groups per quarter-wave (2 lanes/group = conflict-free) instead
// of all 16 lanes on one group (row stride 128 B = 32 banks).
// ---------------------------------------------------------------------------
#define BM 128
#define BN 128
#define BK 64

template <int EPI>
__global__ __launch_bounds__(256, 2) void gemm_nt(
    const unsigned short* __restrict__ A, const unsigned short* __restrict__ Bm,
    unsigned short* __restrict__ Cbf, float* __restrict__ Cf,
    const float* __restrict__ ident, int M, int N, int K) {
  __shared__ unsigned short lA[BM * BK];
  __shared__ unsigned short lB[BN * BK];
  const int tid  = threadIdx.x;
  const int lane = tid & 63;
  const int wave = tid >> 6;
  const int wm = (wave >> 1) << 6;  // wave row offset in tile
  const int wn = (wave & 1) << 6;   // wave col offset in tile
  const int tM = blockIdx.y * BM;
  const int tN = blockIdx.x * BN;

  f32x4 acc[4][4];
  #pragma unroll
  for (int i = 0; i < 4; ++i)
    #pragma unroll
    for (int j = 0; j < 4; ++j) acc[i][j] = f32x4{0.f, 0.f, 0.f, 0.f};

  const unsigned short* Ab = A + (size_t)tM * K;
  const unsigned short* Bb = Bm + (size_t)tN * K;

  for (int k0 = 0; k0 < K; k0 += BK) {
    // Stage A and B tiles (128x64 bf16 = 16 KB each): 4 x 16B per thread each.
    // Swizzled source: slot s8 of row gets global chunk s8 ^ (row & 7).
    #pragma unroll
    for (int i = 0; i < 4; ++i) {
      const int t8  = i * 256 + tid;
      const int row = t8 >> 3;           // 8 chunks of 16B per 64-elem row
      const int s8  = t8 & 7;
      const int col = ((s8 ^ (row & 7)) << 3);
      __builtin_amdgcn_global_load_lds(
          (const __attribute__((address_space(1))) void*)(Ab + (size_t)row * K + k0 + col),
          (__attribute__((address_space(3))) void*)(&lA[t8 << 3]), 16, 0, 0);
      __builtin_amdgcn_global_load_lds(
          (const __attribute__((address_space(1))) void*)(Bb + (size_t)row * K + k0 + col),
          (__attribute__((address_space(3))) void*)(&lB[t8 << 3]), 16, 0, 0);
    }
    __syncthreads();

    #pragma unroll
    for (int kk = 0; kk < BK; kk += 32) {
      const int r0 = lane & 15;
      // chunk index within BK=64: c8 = kk/8 + quarter-wave; swizzle by r0&7
      const int s8 = (((kk >> 3) + (lane >> 4)) ^ (r0 & 7)) << 3;
      bf16x8 af[4], bfr[4];
      #pragma unroll
      for (int i = 0; i < 4; ++i)
        af[i] = *reinterpret_cast<const bf16x8*>(&lA[(wm + i * 16 + r0) * BK + s8]);
      #pragma unroll
      for (int j = 0; j < 4; ++j)
        bfr[j] = *reinterpret_cast<const bf16x8*>(&lB[(wn + j * 16 + r0) * BK + s8]);
      #pragma unroll
      for (int i = 0; i < 4; ++i)
        #pragma unroll
        for (int j = 0; j < 4; ++j)
          acc[i][j] = __builtin_amdgcn_mfma_f32_16x16x32_bf16(af[i], bfr[j], acc[i][j], 0, 0, 0);
    }
    __syncthreads();
  }

  // Epilogue. C/D layout: col = lane&15, row = (lane>>4)*4 + reg.
  const int cn = tN + wn + (lane & 15);
  const int rm = tM + wm + ((lane >> 4) << 2);
  #pragma unroll
  for (int i = 0; i < 4; ++i) {
    #pragma unroll
    for (int r = 0; r < 4; ++r) {
      const size_t rowoff = (size_t)(rm + i * 16 + r) * N;
      #pragma unroll
      for (int j = 0; j < 4; ++j) {
        const size_t idx = rowoff + cn + j * 16;
        const float v = acc[i][j][r];
        if (EPI == 0) {
          Cbf[idx] = f2bf(v);
        } else {
          Cf[idx] = v + ident[idx];
        }
      }
    }
  }
}

// ---------------------------------------------------------------------------
// Launch. Workspace layout (needs ~210 MB):
//   [0, 32MB)    xn bf16 [8192][2048]      (overlaid by act after GEMM1)
//   [32, 64MB)   W_in bf16 [8192][2048]    (overlaid by act after GEMM1)
//   [64, 80MB)   W_out bf16 [2048][4096]
//   [80MB, +16K) dt_weights fp32 [4096]
//   [81MB, +128MB) projected bf16 [8192][8192]
//   act bf16 [8192][4096] = 64MB overlays [0, 64MB)
// ---------------------------------------------------------------------------
extern "C" void kernel_launch(void* const* d_in, const int* in_sizes, int n_in,
                              void* d_out, int out_size, void* d_ws, size_t ws_size,
                              hipStream_t stream) {
  const float* x     = (const float*)d_in[0];
  const float* gamma = (const float*)d_in[1];
  const float* beta  = (const float*)d_in[2];
  const float* W_in  = (const float*)d_in[3];
  const float* W_out = (const float*)d_in[4];
  const float* dt    = (const float*)d_in[5];
  float* out = (float*)d_out;

  char* ws = (char*)d_ws;
  unsigned short* xn     = (unsigned short*)(ws);
  unsigned short* win_b  = (unsigned short*)(ws + ((size_t)32 << 20));
  unsigned short* wout_b = (unsigned short*)(ws + ((size_t)64 << 20));
  float*          dtw    = (float*)(ws + ((size_t)80 << 20));
  unsigned short* proj   = (unsigned short*)(ws + ((size_t)81 << 20));
  unsigned short* act    = (unsigned short*)(ws);  // overlays xn+W_in after GEMM1

  ln_kernel<<<T_TOK, 256, 0, stream>>>(x, gamma, beta, xn);
  cvt_bf16<<<(TWO_DI * DM / 4 + 255) / 256, 256, 0, stream>>>(W_in, win_b, TWO_DI * DM / 4);
  cvt_bf16<<<(DM * DI / 4 + 255) / 256, 256, 0, stream>>>(W_out, wout_b, DM * DI / 4);
  dt_softmax<<<1, 256, 0, stream>>>(dt, dtw);

  // GEMM1: proj[t,e] = sum_d xn[t,d] * W_in[e,d]   (M=8192, N=8192, K=2048)
  gemm_nt<0><<<dim3(TWO_DI / BN, T_TOK / BM), 256, 0, stream>>>(
      xn, win_b, proj, nullptr, nullptr, T_TOK, TWO_DI, DM);

  // Activation: act[t,e] = f(z, gate) * dtw[e]
  act_kernel<<<T_TOK * DI / 4 / 256, 256, 0, stream>>>(proj, dtw, act);

  // GEMM2: out[t,d] = sum_e act[t,e] * W_out[d,e] + x[t,d]  (M=8192, N=2048, K=4096)
  gemm_nt<1><<<dim3(DM / BN, T_TOK / BM), 256, 0, stream>>>(
      act, wout_b, nullptr, out, x, T_TOK, DM, DI);
}

// Round 3
// 602.640 us; speedup vs baseline: 1.2015x; 1.0031x over previous
//
#include <hip/hip_runtime.h>
#include <cstdint>
#include <cstddef>

// Problem constants
#define T_TOK 8192    // B*S tokens
#define DM    2048    // d_model
#define DI    4096    // d_inner
#define TWO_DI 8192

typedef __attribute__((ext_vector_type(8))) short bf16x8;
typedef __attribute__((ext_vector_type(4))) float f32x4;

__device__ __forceinline__ unsigned short f2bf(float f) {
  union { float f; unsigned u; } c; c.f = f;
  unsigned u = c.u;
  unsigned r = (u + 0x7fffu + ((u >> 16) & 1u)) >> 16;  // RNE
  return (unsigned short)r;
}
__device__ __forceinline__ float bf2f(unsigned short b) {
  union { unsigned u; float f; } c; c.u = ((unsigned)b) << 16;
  return c.f;
}

// ---------------------------------------------------------------------------
// LayerNorm over last dim (2048) + cast to bf16. One block per token.
// ---------------------------------------------------------------------------
__global__ __launch_bounds__(256) void ln_kernel(
    const float* __restrict__ x, const float* __restrict__ gamma,
    const float* __restrict__ beta, unsigned short* __restrict__ xn) {
  const int t = blockIdx.x;
  const int tid = threadIdx.x;
  const float* row = x + (size_t)t * DM;
  float4 v0 = reinterpret_cast<const float4*>(row)[tid];
  float4 v1 = reinterpret_cast<const float4*>(row)[tid + 256];
  float s  = v0.x + v0.y + v0.z + v0.w + v1.x + v1.y + v1.z + v1.w;
  float ss = v0.x*v0.x + v0.y*v0.y + v0.z*v0.z + v0.w*v0.w
           + v1.x*v1.x + v1.y*v1.y + v1.z*v1.z + v1.w*v1.w;
  #pragma unroll
  for (int off = 32; off > 0; off >>= 1) {
    s  += __shfl_down(s, off);
    ss += __shfl_down(ss, off);
  }
  __shared__ float red[8];
  __shared__ float mu_s, inv_s;
  if ((tid & 63) == 0) { red[tid >> 6] = s; red[4 + (tid >> 6)] = ss; }
  __syncthreads();
  if (tid == 0) {
    float S  = red[0] + red[1] + red[2] + red[3];
    float SS = red[4] + red[5] + red[6] + red[7];
    float mu  = S * (1.0f / DM);
    float var = SS * (1.0f / DM) - mu * mu;
    mu_s = mu;
    inv_s = rsqrtf(var + 1e-5f);
  }
  __syncthreads();
  const float mu = mu_s, inv = inv_s;
  float4 g0 = reinterpret_cast<const float4*>(gamma)[tid];
  float4 b0 = reinterpret_cast<const float4*>(beta)[tid];
  float4 g1 = reinterpret_cast<const float4*>(gamma)[tid + 256];
  float4 b1 = reinterpret_cast<const float4*>(beta)[tid + 256];
  ushort4 o0, o1;
  o0.x = f2bf((v0.x - mu) * inv * g0.x + b0.x);
  o0.y = f2bf((v0.y - mu) * inv * g0.y + b0.y);
  o0.z = f2bf((v0.z - mu) * inv * g0.z + b0.z);
  o0.w = f2bf((v0.w - mu) * inv * g0.w + b0.w);
  o1.x = f2bf((v1.x - mu) * inv * g1.x + b1.x);
  o1.y = f2bf((v1.y - mu) * inv * g1.y + b1.y);
  o1.z = f2bf((v1.z - mu) * inv * g1.z + b1.z);
  o1.w = f2bf((v1.w - mu) * inv * g1.w + b1.w);
  reinterpret_cast<ushort4*>(xn + (size_t)t * DM)[tid]       = o0;
  reinterpret_cast<ushort4*>(xn + (size_t)t * DM)[tid + 256] = o1;
}

// ---------------------------------------------------------------------------
// fp32 -> bf16 conversion (vectorized x4)
// ---------------------------------------------------------------------------
__global__ __launch_bounds__(256) void cvt_bf16(
    const float* __restrict__ in, unsigned short* __restrict__ out, int n4) {
  int i = blockIdx.x * 256 + threadIdx.x;
  if (i >= n4) return;
  float4 v = reinterpret_cast<const float4*>(in)[i];
  ushort4 o;
  o.x = f2bf(v.x); o.y = f2bf(v.y); o.z = f2bf(v.z); o.w = f2bf(v.w);
  reinterpret_cast<ushort4*>(out)[i] = o;
}

// ---------------------------------------------------------------------------
// softmax(-dt) over 4096 elems. Single block.
// ---------------------------------------------------------------------------
__global__ __launch_bounds__(256) void dt_softmax(
    const float* __restrict__ dt, float* __restrict__ w) {
  const int tid = threadIdx.x;
  float e[16];
  float local = 0.f;
  #pragma unroll
  for (int i = 0; i < 16; ++i) {
    float v = __expf(-dt[i * 256 + tid]);
    e[i] = v;
    local += v;
  }
  #pragma unroll
  for (int off = 32; off > 0; off >>= 1) local += __shfl_down(local, off);
  __shared__ float red[4];
  __shared__ float tot;
  if ((tid & 63) == 0) red[tid >> 6] = local;
  __syncthreads();
  if (tid == 0) tot = red[0] + red[1] + red[2] + red[3];
  __syncthreads();
  const float inv = 1.f / tot;
  #pragma unroll
  for (int i = 0; i < 16; ++i) w[i * 256 + tid] = e[i] * inv;
}

__device__ __forceinline__ float actf(float z, float g, float w) {
  float zc = fminf(fmaxf(z, -15.f), 15.f);
  float sz = 1.f / (1.f + __expf(-zc));
  float gc = fminf(fmaxf(g, -15.f), 15.f);
  float sg = 1.f / (1.f + __expf(-gc));
  return z * sz * w * gc * sg;
}

#define BM 128
#define BN 128
#define BK 64

// ---------------------------------------------------------------------------
// GEMM1 fused with gated activation.
// act[t,n] = f(z,g)*dtw[n], z = A.W_in[n,:], g = A.W_in[n+DI,:]
// 512 threads = 8 waves. Waves 0-3 compute the 128x128 z-tile (2x2 wave grid,
// 64x64 each via 4x4 16x16x32 MFMA); waves 4-7 the matching gate-tile.
// One shared A-tile stage + two B-tile stages per k0 (48 KB LDS, XOR-swizzled
// chunks as in gemm_nt). Epilogue: gate waves publish C through a 64x132
// fp32 LDS exchange (2 row-half phases; stride 132 -> 2-way bank alias, free),
// z waves combine and store bf16 act directly. Kills the 256 MB proj
// round-trip and the separate act kernel.
// ---------------------------------------------------------------------------
__global__ __launch_bounds__(512, 2) void gemm1_fused(
    const unsigned short* __restrict__ A, const unsigned short* __restrict__ W,
    const float* __restrict__ dtw, unsigned short* __restrict__ act) {
  __shared__ unsigned short lds[3 * BM * BK];  // lA | lB1 | lB2 ; Xbuf aliases
  unsigned short* lA  = lds;
  unsigned short* lB1 = lds + BM * BK;
  unsigned short* lB2 = lds + 2 * BM * BK;
  float* Xbuf = reinterpret_cast<float*>(lds);  // 64 x 132 fp32 = 33 KB

  const int tid  = threadIdx.x;
  const int lane = tid & 63;
  const int wave = tid >> 6;       // 0..7
  const int wq   = wave & 3;
  const int wm   = (wq >> 1) << 6;
  const int wn   = (wq & 1) << 6;
  const bool isZ = wave < 4;
  const int tM = blockIdx.y * BM;
  const int tN = blockIdx.x * BN;  // [0, DI)

  f32x4 acc[4][4];
  #pragma unroll
  for (int i = 0; i < 4; ++i)
    #pragma unroll
    for (int j = 0; j < 4; ++j) acc[i][j] = f32x4{0.f, 0.f, 0.f, 0.f};

  const unsigned short* Ab = A + (size_t)tM * DM;
  const unsigned short* B1 = W + (size_t)tN * DM;
  const unsigned short* B2 = W + (size_t)(tN + DI) * DM;
  const unsigned short* lB = isZ ? lB1 : lB2;

  for (int k0 = 0; k0 < DM; k0 += BK) {
    // Stage A, B1, B2 (each 128x64 bf16 = 1024 16B chunks over 512 threads).
    // Swizzled source: LDS slot s8 of row holds global chunk s8 ^ (row & 7).
    #pragma unroll
    for (int i = 0; i < 2; ++i) {
      const int t8  = i * 512 + tid;
      const int row = t8 >> 3;
      const int s8  = t8 & 7;
      const int col = ((s8 ^ (row & 7)) << 3);
      __builtin_amdgcn_global_load_lds(
          (const __attribute__((address_space(1))) void*)(Ab + (size_t)row * DM + k0 + col),
          (__attribute__((address_space(3))) void*)(&lA[t8 << 3]), 16, 0, 0);
      __builtin_amdgcn_global_load_lds(
          (const __attribute__((address_space(1))) void*)(B1 + (size_t)row * DM + k0 + col),
          (__attribute__((address_space(3))) void*)(&lB1[t8 << 3]), 16, 0, 0);
      __builtin_amdgcn_global_load_lds(
          (const __attribute__((address_space(1))) void*)(B2 + (size_t)row * DM + k0 + col),
          (__attribute__((address_space(3))) void*)(&lB2[t8 << 3]), 16, 0, 0);
    }
    __syncthreads();

    #pragma unroll
    for (int kk = 0; kk < BK; kk += 32) {
      const int r0 = lane & 15;
      const int s8 = (((kk >> 3) + (lane >> 4)) ^ (r0 & 7)) << 3;
      bf16x8 af[4], bfr[4];
      #pragma unroll
      for (int i = 0; i < 4; ++i)
        af[i] = *reinterpret_cast<const bf16x8*>(&lA[(wm + i * 16 + r0) * BK + s8]);
      #pragma unroll
      for (int j = 0; j < 4; ++j)
        bfr[j] = *reinterpret_cast<const bf16x8*>(&lB[(wn + j * 16 + r0) * BK + s8]);
      #pragma unroll
      for (int i = 0; i < 4; ++i)
        #pragma unroll
        for (int j = 0; j < 4; ++j)
          acc[i][j] = __builtin_amdgcn_mfma_f32_16x16x32_bf16(af[i], bfr[j], acc[i][j], 0, 0, 0);
    }
    __syncthreads();
  }

  // ------ fused epilogue ------
  // C/D layout: col = lane&15 (+wn+j*16), local row = (lane>>4)*4 + r (+i*16).
  const int c15 = lane & 15;
  const int qr  = (lane >> 4) << 2;

  // Phase 1: gate waves 4,5 (wm=0) publish rows 0..63
  if (wave == 4 || wave == 5) {
    #pragma unroll
    for (int i = 0; i < 4; ++i)
      #pragma unroll
      for (int r = 0; r < 4; ++r) {
        const int lr = i * 16 + qr + r;
        #pragma unroll
        for (int j = 0; j < 4; ++j)
          Xbuf[lr * 132 + wn + j * 16 + c15] = acc[i][j][r];
      }
  }
  __syncthreads();
  // Phase 2: z waves 0,1 (wm=0) combine + store rows 0..63
  if (wave == 0 || wave == 1) {
    float w4[4];
    #pragma unroll
    for (int j = 0; j < 4; ++j) w4[j] = dtw[tN + wn + j * 16 + c15];
    #pragma unroll
    for (int i = 0; i < 4; ++i)
      #pragma unroll
      for (int r = 0; r < 4; ++r) {
        const int lr = i * 16 + qr + r;
        const size_t rowoff = (size_t)(tM + lr) * DI + tN + wn + c15;
        #pragma unroll
        for (int j = 0; j < 4; ++j) {
          const float g = Xbuf[lr * 132 + wn + j * 16 + c15];
          act[rowoff + j * 16] = f2bf(actf(acc[i][j][r], g, w4[j]));
        }
      }
  }
  __syncthreads();
  // Phase 3: gate waves 6,7 (wm=64) publish rows 64..127 (local 0..63)
  if (wave == 6 || wave == 7) {
    #pragma unroll
    for (int i = 0; i < 4; ++i)
      #pragma unroll
      for (int r = 0; r < 4; ++r) {
        const int lr = i * 16 + qr + r;
        #pragma unroll
        for (int j = 0; j < 4; ++j)
          Xbuf[lr * 132 + wn + j * 16 + c15] = acc[i][j][r];
      }
  }
  __syncthreads();
  // Phase 4: z waves 2,3 (wm=64) combine + store rows 64..127
  if (wave == 2 || wave == 3) {
    float w4[4];
    #pragma unroll
    for (int j = 0; j < 4; ++j) w4[j] = dtw[tN + wn + j * 16 + c15];
    #pragma unroll
    for (int i = 0; i < 4; ++i)
      #pragma unroll
      for (int r = 0; r < 4; ++r) {
        const int lr = i * 16 + qr + r;
        const size_t rowoff = (size_t)(tM + 64 + lr) * DI + tN + wn + c15;
        #pragma unroll
        for (int j = 0; j < 4; ++j) {
          const float g = Xbuf[lr * 132 + wn + j * 16 + c15];
          act[rowoff + j * 16] = f2bf(actf(acc[i][j][r], g, w4[j]));
        }
      }
  }
}

// ---------------------------------------------------------------------------
// NT bf16 GEMM (m97 recipe + XOR-swizzled LDS): C[m,n] = sum_k A[m,k]*B[n,k]
// Used for GEMM2 with fused residual epilogue (fp32 out).
// ---------------------------------------------------------------------------
__global__ __launch_bounds__(256, 2) void gemm_nt_res(
    const unsigned short* __restrict__ A, const unsigned short* __restrict__ Bm,
    float* __restrict__ Cf, const float* __restrict__ ident, int M, int N, int K) {
  __shared__ unsigned short lA[BM * BK];
  __shared__ unsigned short lB[BN * BK];
  const int tid  = threadIdx.x;
  const int lane = tid & 63;
  const int wave = tid >> 6;
  const int wm = (wave >> 1) << 6;
  const int wn = (wave & 1) << 6;
  const int tM = blockIdx.y * BM;
  const int tN = blockIdx.x * BN;

  f32x4 acc[4][4];
  #pragma unroll
  for (int i = 0; i < 4; ++i)
    #pragma unroll
    for (int j = 0; j < 4; ++j) acc[i][j] = f32x4{0.f, 0.f, 0.f, 0.f};

  const unsigned short* Ab = A + (size_t)tM * K;
  const unsigned short* Bb = Bm + (size_t)tN * K;

  for (int k0 = 0; k0 < K; k0 += BK) {
    #pragma unroll
    for (int i = 0; i < 4; ++i) {
      const int t8  = i * 256 + tid;
      const int row = t8 >> 3;
      const int s8  = t8 & 7;
      const int col = ((s8 ^ (row & 7)) << 3);
      __builtin_amdgcn_global_load_lds(
          (const __attribute__((address_space(1))) void*)(Ab + (size_t)row * K + k0 + col),
          (__attribute__((address_space(3))) void*)(&lA[t8 << 3]), 16, 0, 0);
      __builtin_amdgcn_global_load_lds(
          (const __attribute__((address_space(1))) void*)(Bb + (size_t)row * K + k0 + col),
          (__attribute__((address_space(3))) void*)(&lB[t8 << 3]), 16, 0, 0);
    }
    __syncthreads();

    #pragma unroll
    for (int kk = 0; kk < BK; kk += 32) {
      const int r0 = lane & 15;
      const int s8 = (((kk >> 3) + (lane >> 4)) ^ (r0 & 7)) << 3;
      bf16x8 af[4], bfr[4];
      #pragma unroll
      for (int i = 0; i < 4; ++i)
        af[i] = *reinterpret_cast<const bf16x8*>(&lA[(wm + i * 16 + r0) * BK + s8]);
      #pragma unroll
      for (int j = 0; j < 4; ++j)
        bfr[j] = *reinterpret_cast<const bf16x8*>(&lB[(wn + j * 16 + r0) * BK + s8]);
      #pragma unroll
      for (int i = 0; i < 4; ++i)
        #pragma unroll
        for (int j = 0; j < 4; ++j)
          acc[i][j] = __builtin_amdgcn_mfma_f32_16x16x32_bf16(af[i], bfr[j], acc[i][j], 0, 0, 0);
    }
    __syncthreads();
  }

  const int cn = tN + wn + (lane & 15);
  const int rm = tM + wm + ((lane >> 4) << 2);
  #pragma unroll
  for (int i = 0; i < 4; ++i) {
    #pragma unroll
    for (int r = 0; r < 4; ++r) {
      const size_t rowoff = (size_t)(rm + i * 16 + r) * N;
      #pragma unroll
      for (int j = 0; j < 4; ++j) {
        const size_t idx = rowoff + cn + j * 16;
        Cf[idx] = acc[i][j][r] + ident[idx];
      }
    }
  }
}

// ---------------------------------------------------------------------------
// Workspace layout (~160 MB):
//   [0, 32MB)     xn bf16 [8192][2048]
//   [32, 64MB)    W_in bf16 [8192][2048]
//   [64, 80MB)    W_out bf16 [2048][4096]
//   [80MB, +16K)  dt_weights fp32 [4096]
//   [96, 160MB)   act bf16 [8192][4096]
// ---------------------------------------------------------------------------
extern "C" void kernel_launch(void* const* d_in, const int* in_sizes, int n_in,
                              void* d_out, int out_size, void* d_ws, size_t ws_size,
                              hipStream_t stream) {
  const float* x     = (const float*)d_in[0];
  const float* gamma = (const float*)d_in[1];
  const float* beta  = (const float*)d_in[2];
  const float* W_in  = (const float*)d_in[3];
  const float* W_out = (const float*)d_in[4];
  const float* dt    = (const float*)d_in[5];
  float* out = (float*)d_out;

  char* ws = (char*)d_ws;
  unsigned short* xn     = (unsigned short*)(ws);
  unsigned short* win_b  = (unsigned short*)(ws + ((size_t)32 << 20));
  unsigned short* wout_b = (unsigned short*)(ws + ((size_t)64 << 20));
  float*          dtw    = (float*)(ws + ((size_t)80 << 20));
  unsigned short* act    = (unsigned short*)(ws + ((size_t)96 << 20));

  ln_kernel<<<T_TOK, 256, 0, stream>>>(x, gamma, beta, xn);
  cvt_bf16<<<(TWO_DI * DM / 4 + 255) / 256, 256, 0, stream>>>(W_in, win_b, TWO_DI * DM / 4);
  cvt_bf16<<<(DM * DI / 4 + 255) / 256, 256, 0, stream>>>(W_out, wout_b, DM * DI / 4);
  dt_softmax<<<1, 256, 0, stream>>>(dt, dtw);

  // GEMM1 + gated activation fused: act[t,e], e in [0,DI)
  gemm1_fused<<<dim3(DI / BN, T_TOK / BM), 512, 0, stream>>>(xn, win_b, dtw, act);

  // GEMM2: out[t,d] = sum_e act[t,e] * W_out[d,e] + x[t,d]
  gemm_nt_res<<<dim3(DM / BN, T_TOK / BM), 256, 0, stream>>>(
      act, wout_b, out, x, T_TOK, DM, DI);
}

// Round 4
// 564.380 us; speedup vs baseline: 1.2829x; 1.0678x over previous
//
#include <hip/hip_runtime.h>
#include <cstdint>
#include <cstddef>

// Problem constants
#define T_TOK 8192    // B*S tokens
#define DM    2048    // d_model
#define DI    4096    // d_inner
#define TWO_DI 8192

typedef __attribute__((ext_vector_type(8))) short bf16x8;
typedef __attribute__((ext_vector_type(4))) float f32x4;

__device__ __forceinline__ unsigned short f2bf(float f) {
  union { float f; unsigned u; } c; c.f = f;
  unsigned u = c.u;
  unsigned r = (u + 0x7fffu + ((u >> 16) & 1u)) >> 16;  // RNE
  return (unsigned short)r;
}
__device__ __forceinline__ float bf2f(unsigned short b) {
  union { unsigned u; float f; } c; c.u = ((unsigned)b) << 16;
  return c.f;
}

// ---------------------------------------------------------------------------
// LayerNorm over last dim (2048) + cast to bf16. One block per token.
// ---------------------------------------------------------------------------
__global__ __launch_bounds__(256) void ln_kernel(
    const float* __restrict__ x, const float* __restrict__ gamma,
    const float* __restrict__ beta, unsigned short* __restrict__ xn) {
  const int t = blockIdx.x;
  const int tid = threadIdx.x;
  const float* row = x + (size_t)t * DM;
  float4 v0 = reinterpret_cast<const float4*>(row)[tid];
  float4 v1 = reinterpret_cast<const float4*>(row)[tid + 256];
  float s  = v0.x + v0.y + v0.z + v0.w + v1.x + v1.y + v1.z + v1.w;
  float ss = v0.x*v0.x + v0.y*v0.y + v0.z*v0.z + v0.w*v0.w
           + v1.x*v1.x + v1.y*v1.y + v1.z*v1.z + v1.w*v1.w;
  #pragma unroll
  for (int off = 32; off > 0; off >>= 1) {
    s  += __shfl_down(s, off);
    ss += __shfl_down(ss, off);
  }
  __shared__ float red[8];
  __shared__ float mu_s, inv_s;
  if ((tid & 63) == 0) { red[tid >> 6] = s; red[4 + (tid >> 6)] = ss; }
  __syncthreads();
  if (tid == 0) {
    float S  = red[0] + red[1] + red[2] + red[3];
    float SS = red[4] + red[5] + red[6] + red[7];
    float mu  = S * (1.0f / DM);
    float var = SS * (1.0f / DM) - mu * mu;
    mu_s = mu;
    inv_s = rsqrtf(var + 1e-5f);
  }
  __syncthreads();
  const float mu = mu_s, inv = inv_s;
  float4 g0 = reinterpret_cast<const float4*>(gamma)[tid];
  float4 b0 = reinterpret_cast<const float4*>(beta)[tid];
  float4 g1 = reinterpret_cast<const float4*>(gamma)[tid + 256];
  float4 b1 = reinterpret_cast<const float4*>(beta)[tid + 256];
  ushort4 o0, o1;
  o0.x = f2bf((v0.x - mu) * inv * g0.x + b0.x);
  o0.y = f2bf((v0.y - mu) * inv * g0.y + b0.y);
  o0.z = f2bf((v0.z - mu) * inv * g0.z + b0.z);
  o0.w = f2bf((v0.w - mu) * inv * g0.w + b0.w);
  o1.x = f2bf((v1.x - mu) * inv * g1.x + b1.x);
  o1.y = f2bf((v1.y - mu) * inv * g1.y + b1.y);
  o1.z = f2bf((v1.z - mu) * inv * g1.z + b1.z);
  o1.w = f2bf((v1.w - mu) * inv * g1.w + b1.w);
  reinterpret_cast<ushort4*>(xn + (size_t)t * DM)[tid]       = o0;
  reinterpret_cast<ushort4*>(xn + (size_t)t * DM)[tid + 256] = o1;
}

// ---------------------------------------------------------------------------
// fp32 -> bf16 conversion for BOTH weight matrices in one launch.
// ---------------------------------------------------------------------------
__global__ __launch_bounds__(256) void cvt_both(
    const float* __restrict__ a, unsigned short* __restrict__ oa, int n4a,
    const float* __restrict__ b, unsigned short* __restrict__ ob, int n4b) {
  int i = blockIdx.x * 256 + threadIdx.x;
  const float* src;
  unsigned short* dst;
  int idx;
  if (i < n4a) { src = a; dst = oa; idx = i; }
  else { idx = i - n4a; if (idx >= n4b) return; src = b; dst = ob; }
  float4 v = reinterpret_cast<const float4*>(src)[idx];
  ushort4 o;
  o.x = f2bf(v.x); o.y = f2bf(v.y); o.z = f2bf(v.z); o.w = f2bf(v.w);
  reinterpret_cast<ushort4*>(dst)[idx] = o;
}

// ---------------------------------------------------------------------------
// softmax(-dt) over 4096 elems. Single block.
// ---------------------------------------------------------------------------
__global__ __launch_bounds__(256) void dt_softmax(
    const float* __restrict__ dt, float* __restrict__ w) {
  const int tid = threadIdx.x;
  float e[16];
  float local = 0.f;
  #pragma unroll
  for (int i = 0; i < 16; ++i) {
    float v = __expf(-dt[i * 256 + tid]);
    e[i] = v;
    local += v;
  }
  #pragma unroll
  for (int off = 32; off > 0; off >>= 1) local += __shfl_down(local, off);
  __shared__ float red[4];
  __shared__ float tot;
  if ((tid & 63) == 0) red[tid >> 6] = local;
  __syncthreads();
  if (tid == 0) tot = red[0] + red[1] + red[2] + red[3];
  __syncthreads();
  const float inv = 1.f / tot;
  #pragma unroll
  for (int i = 0; i < 16; ++i) w[i * 256 + tid] = e[i] * inv;
}

__device__ __forceinline__ float actf(float z, float g, float w) {
  float zc = fminf(fmaxf(z, -15.f), 15.f);
  float sz = 1.f / (1.f + __expf(-zc));
  float gc = fminf(fmaxf(g, -15.f), 15.f);
  float sg = 1.f / (1.f + __expf(-gc));
  return z * sz * w * gc * sg;
}

#define BM 128
#define BN 128
#define BK 64

// ---------------------------------------------------------------------------
// GEMM1 fused with gated activation — register-dual-tile version.
// act[t,n] = f(z,g)*dtw[n], z = A.W_in[n,:], g = A.W_in[n+DI,:]
// 256 threads = 4 waves (2x2), each wave holds BOTH the z 64x64 and gate
// 64x64 accumulators (4x4 f32x4 each = 128 acc VGPRs). Per K-step a block
// stages A,B1,B2 (48 KB) and issues 256 MFMAs -> 2.15x MFMA:LDS ratio vs
// the split-wave design. Epilogue is pure register math (z and g for the
// same (m,n) live in the same lane) — no LDS exchange.
// Occupancy: ~2 waves/SIMD (caps at 256 VGPR via launch_bounds), 2 blocks/CU;
// cross-block overlap covers barrier drains.
// ---------------------------------------------------------------------------
__global__ __launch_bounds__(256, 2) void gemm1_fused(
    const unsigned short* __restrict__ A, const unsigned short* __restrict__ W,
    const float* __restrict__ dtw, unsigned short* __restrict__ act) {
  __shared__ unsigned short lA[BM * BK];
  __shared__ unsigned short lB1[BN * BK];
  __shared__ unsigned short lB2[BN * BK];

  const int tid  = threadIdx.x;
  const int lane = tid & 63;
  const int wave = tid >> 6;       // 0..3
  const int wm   = (wave >> 1) << 6;
  const int wn   = (wave & 1) << 6;
  const int tM = blockIdx.y * BM;
  const int tN = blockIdx.x * BN;  // [0, DI)

  f32x4 accZ[4][4], accG[4][4];
  #pragma unroll
  for (int i = 0; i < 4; ++i)
    #pragma unroll
    for (int j = 0; j < 4; ++j) {
      accZ[i][j] = f32x4{0.f, 0.f, 0.f, 0.f};
      accG[i][j] = f32x4{0.f, 0.f, 0.f, 0.f};
    }

  const unsigned short* Ab = A + (size_t)tM * DM;
  const unsigned short* B1 = W + (size_t)tN * DM;
  const unsigned short* B2 = W + (size_t)(tN + DI) * DM;

  for (int k0 = 0; k0 < DM; k0 += BK) {
    // Stage A, B1, B2: 1024 16B chunks each over 256 threads (4 per tile).
    // XOR swizzle: LDS slot s8 of row holds global chunk s8 ^ (row & 7).
    #pragma unroll
    for (int i = 0; i < 4; ++i) {
      const int t8  = i * 256 + tid;
      const int row = t8 >> 3;
      const int s8  = t8 & 7;
      const int col = ((s8 ^ (row & 7)) << 3);
      const size_t goff = (size_t)row * DM + k0 + col;
      __builtin_amdgcn_global_load_lds(
          (const __attribute__((address_space(1))) void*)(Ab + goff),
          (__attribute__((address_space(3))) void*)(&lA[t8 << 3]), 16, 0, 0);
      __builtin_amdgcn_global_load_lds(
          (const __attribute__((address_space(1))) void*)(B1 + goff),
          (__attribute__((address_space(3))) void*)(&lB1[t8 << 3]), 16, 0, 0);
      __builtin_amdgcn_global_load_lds(
          (const __attribute__((address_space(1))) void*)(B2 + goff),
          (__attribute__((address_space(3))) void*)(&lB2[t8 << 3]), 16, 0, 0);
    }
    __syncthreads();

    #pragma unroll
    for (int kk = 0; kk < BK; kk += 32) {
      const int r0 = lane & 15;
      const int s8 = (((kk >> 3) + (lane >> 4)) ^ (r0 & 7)) << 3;
      bf16x8 af[4], b1f[4], b2f[4];
      #pragma unroll
      for (int i = 0; i < 4; ++i)
        af[i] = *reinterpret_cast<const bf16x8*>(&lA[(wm + i * 16 + r0) * BK + s8]);
      #pragma unroll
      for (int j = 0; j < 4; ++j) {
        b1f[j] = *reinterpret_cast<const bf16x8*>(&lB1[(wn + j * 16 + r0) * BK + s8]);
        b2f[j] = *reinterpret_cast<const bf16x8*>(&lB2[(wn + j * 16 + r0) * BK + s8]);
      }
      #pragma unroll
      for (int i = 0; i < 4; ++i)
        #pragma unroll
        for (int j = 0; j < 4; ++j) {
          accZ[i][j] = __builtin_amdgcn_mfma_f32_16x16x32_bf16(af[i], b1f[j], accZ[i][j], 0, 0, 0);
          accG[i][j] = __builtin_amdgcn_mfma_f32_16x16x32_bf16(af[i], b2f[j], accG[i][j], 0, 0, 0);
        }
    }
    __syncthreads();
  }

  // Register epilogue. C/D layout: col = lane&15, row = (lane>>4)*4 + reg.
  const int c15 = lane & 15;
  const int qr  = (lane >> 4) << 2;
  float w4[4];
  #pragma unroll
  for (int j = 0; j < 4; ++j) w4[j] = dtw[tN + wn + j * 16 + c15];
  #pragma unroll
  for (int i = 0; i < 4; ++i) {
    #pragma unroll
    for (int r = 0; r < 4; ++r) {
      const size_t rowoff = (size_t)(tM + wm + i * 16 + qr + r) * DI + tN + wn + c15;
      #pragma unroll
      for (int j = 0; j < 4; ++j)
        act[rowoff + j * 16] = f2bf(actf(accZ[i][j][r], accG[i][j][r], w4[j]));
    }
  }
}

// ---------------------------------------------------------------------------
// NT bf16 GEMM (m97 recipe + XOR-swizzled LDS): C[m,n] = sum_k A[m,k]*B[n,k]
// Used for GEMM2 with fused residual epilogue (fp32 out).
// ---------------------------------------------------------------------------
__global__ __launch_bounds__(256, 2) void gemm_nt_res(
    const unsigned short* __restrict__ A, const unsigned short* __restrict__ Bm,
    float* __restrict__ Cf, const float* __restrict__ ident, int M, int N, int K) {
  __shared__ unsigned short lA[BM * BK];
  __shared__ unsigned short lB[BN * BK];
  const int tid  = threadIdx.x;
  const int lane = tid & 63;
  const int wave = tid >> 6;
  const int wm = (wave >> 1) << 6;
  const int wn = (wave & 1) << 6;
  const int tM = blockIdx.y * BM;
  const int tN = blockIdx.x * BN;

  f32x4 acc[4][4];
  #pragma unroll
  for (int i = 0; i < 4; ++i)
    #pragma unroll
    for (int j = 0; j < 4; ++j) acc[i][j] = f32x4{0.f, 0.f, 0.f, 0.f};

  const unsigned short* Ab = A + (size_t)tM * K;
  const unsigned short* Bb = Bm + (size_t)tN * K;

  for (int k0 = 0; k0 < K; k0 += BK) {
    #pragma unroll
    for (int i = 0; i < 4; ++i) {
      const int t8  = i * 256 + tid;
      const int row = t8 >> 3;
      const int s8  = t8 & 7;
      const int col = ((s8 ^ (row & 7)) << 3);
      __builtin_amdgcn_global_load_lds(
          (const __attribute__((address_space(1))) void*)(Ab + (size_t)row * K + k0 + col),
          (__attribute__((address_space(3))) void*)(&lA[t8 << 3]), 16, 0, 0);
      __builtin_amdgcn_global_load_lds(
          (const __attribute__((address_space(1))) void*)(Bb + (size_t)row * K + k0 + col),
          (__attribute__((address_space(3))) void*)(&lB[t8 << 3]), 16, 0, 0);
    }
    __syncthreads();

    #pragma unroll
    for (int kk = 0; kk < BK; kk += 32) {
      const int r0 = lane & 15;
      const int s8 = (((kk >> 3) + (lane >> 4)) ^ (r0 & 7)) << 3;
      bf16x8 af[4], bfr[4];
      #pragma unroll
      for (int i = 0; i < 4; ++i)
        af[i] = *reinterpret_cast<const bf16x8*>(&lA[(wm + i * 16 + r0) * BK + s8]);
      #pragma unroll
      for (int j = 0; j < 4; ++j)
        bfr[j] = *reinterpret_cast<const bf16x8*>(&lB[(wn + j * 16 + r0) * BK + s8]);
      #pragma unroll
      for (int i = 0; i < 4; ++i)
        #pragma unroll
        for (int j = 0; j < 4; ++j)
          acc[i][j] = __builtin_amdgcn_mfma_f32_16x16x32_bf16(af[i], bfr[j], acc[i][j], 0, 0, 0);
    }
    __syncthreads();
  }

  const int cn = tN + wn + (lane & 15);
  const int rm = tM + wm + ((lane >> 4) << 2);
  #pragma unroll
  for (int i = 0; i < 4; ++i) {
    #pragma unroll
    for (int r = 0; r < 4; ++r) {
      const size_t rowoff = (size_t)(rm + i * 16 + r) * N;
      #pragma unroll
      for (int j = 0; j < 4; ++j) {
        const size_t idx = rowoff + cn + j * 16;
        Cf[idx] = acc[i][j][r] + ident[idx];
      }
    }
  }
}

// ---------------------------------------------------------------------------
// Workspace layout (~160 MB):
//   [0, 32MB)     xn bf16 [8192][2048]
//   [32, 64MB)    W_in bf16 [8192][2048]
//   [64, 80MB)    W_out bf16 [2048][4096]
//   [80MB, +16K)  dt_weights fp32 [4096]
//   [96, 160MB)   act bf16 [8192][4096]
// ---------------------------------------------------------------------------
extern "C" void kernel_launch(void* const* d_in, const int* in_sizes, int n_in,
                              void* d_out, int out_size, void* d_ws, size_t ws_size,
                              hipStream_t stream) {
  const float* x     = (const float*)d_in[0];
  const float* gamma = (const float*)d_in[1];
  const float* beta  = (const float*)d_in[2];
  const float* W_in  = (const float*)d_in[3];
  const float* W_out = (const float*)d_in[4];
  const float* dt    = (const float*)d_in[5];
  float* out = (float*)d_out;

  char* ws = (char*)d_ws;
  unsigned short* xn     = (unsigned short*)(ws);
  unsigned short* win_b  = (unsigned short*)(ws + ((size_t)32 << 20));
  unsigned short* wout_b = (unsigned short*)(ws + ((size_t)64 << 20));
  float*          dtw    = (float*)(ws + ((size_t)80 << 20));
  unsigned short* act    = (unsigned short*)(ws + ((size_t)96 << 20));

  const int n4_in  = TWO_DI * DM / 4;
  const int n4_out = DM * DI / 4;

  ln_kernel<<<T_TOK, 256, 0, stream>>>(x, gamma, beta, xn);
  cvt_both<<<(n4_in + n4_out + 255) / 256, 256, 0, stream>>>(
      W_in, win_b, n4_in, W_out, wout_b, n4_out);
  dt_softmax<<<1, 256, 0, stream>>>(dt, dtw);

  // GEMM1 + gated activation fused (register-dual-tile): act[t,e], e in [0,DI)
  gemm1_fused<<<dim3(DI / BN, T_TOK / BM), 256, 0, stream>>>(xn, win_b, dtw, act);

  // GEMM2: out[t,d] = sum_e act[t,e] * W_out[d,e] + x[t,d]
  gemm_nt_res<<<dim3(DM / BN, T_TOK / BM), 256, 0, stream>>>(
      act, wout_b, out, x, T_TOK, DM, DI);
}